// Round 10
// baseline (171.047 us; speedup 1.0000x reference)
//
#include <hip/hip_runtime.h>
#include <hip/hip_fp16.h>

#define NLEV 8
#define BASE 512

typedef _Float16 h8 __attribute__((ext_vector_type(8)));
typedef float f4v __attribute__((ext_vector_type(4)));
typedef signed char c8 __attribute__((ext_vector_type(8)));
typedef signed char c16 __attribute__((ext_vector_type(16)));
typedef int  i4v __attribute__((ext_vector_type(4)));

#define QSCALE 12700.0f

// byte offset of int8 mip level k inside qpyr.
// Level layout (SPLIT): [plane 0..2][feat-half 0..1][v][u] * 8 bytes.
__host__ __device__ __forceinline__ long qoff(int k) {
    return (k == 0) ? 0L : (12582912L + 4194304L - (4194304L >> (2 * k - 2)));
}
#define QPYR_BYTES 16776960L
// fp16 mip staging (halves), k>=1; lives after the int8 pyramid
__host__ __device__ __forceinline__ long moff(int k) {
    return 4194304L - (4194304L >> (2 * k - 2));
}
#define MIPS_HALVES 4194048L

// -------- fused mip build + quantize (split-layout int8) --------------------
__global__ __launch_bounds__(256) void ds16_first(const float* __restrict__ src,
                                                  _Float16* __restrict__ dst,
                                                  signed char* __restrict__ qpyr, int r2) {
    int idx = blockIdx.x * blockDim.x + threadIdx.x;
    int total = 3 * r2 * r2 * 2;
    if (idx >= total) return;
    int g = idx & 1;
    int rest = idx >> 1;
    int u = rest % r2; rest /= r2;
    int v = rest % r2;
    int p = rest / r2;
    int rs = r2 * 2;
    const f4v* s4 = (const f4v*)src;
    long t00 = ((long)p * rs + 2 * v) * rs + 2 * u;
    long t01 = t00 + 1, t10 = t00 + rs, t11 = t10 + 1;
    f4v a0 = s4[t00 * 4 + g * 2], a1 = s4[t00 * 4 + g * 2 + 1];
    f4v b0 = s4[t01 * 4 + g * 2], b1 = s4[t01 * 4 + g * 2 + 1];
    f4v c0 = s4[t10 * 4 + g * 2], c1 = s4[t10 * 4 + g * 2 + 1];
    f4v d0 = s4[t11 * 4 + g * 2], d1 = s4[t11 * 4 + g * 2 + 1];
    h8 o;
    c8 qa, qb_, qc, qd, qo;
#pragma unroll
    for (int j = 0; j < 4; ++j) {
        float m0 = (a0[j] + b0[j] + c0[j] + d0[j]) * 0.25f;
        float m1 = (a1[j] + b1[j] + c1[j] + d1[j]) * 0.25f;
        o[j] = (_Float16)m0; o[4 + j] = (_Float16)m1;
        qo[j] = (signed char)(int)rintf(m0 * QSCALE);
        qo[4 + j] = (signed char)(int)rintf(m1 * QSCALE);
        qa[j] = (signed char)(int)rintf(a0[j] * QSCALE);  qa[4 + j] = (signed char)(int)rintf(a1[j] * QSCALE);
        qb_[j] = (signed char)(int)rintf(b0[j] * QSCALE); qb_[4 + j] = (signed char)(int)rintf(b1[j] * QSCALE);
        qc[j] = (signed char)(int)rintf(c0[j] * QSCALE);  qc[4 + j] = (signed char)(int)rintf(c1[j] * QSCALE);
        qd[j] = (signed char)(int)rintf(d0[j] * QSCALE);  qd[4 + j] = (signed char)(int)rintf(d1[j] * QSCALE);
    }
    ((h8*)dst)[idx] = o;
    // split int8 L0: plane-half base (p*2+g)*512*512, texel (2v,2u)
    long ph = (long)(p * 2 + g) * 262144;
    long w00 = (long)(2 * v) * 512 + 2 * u;
    c16 Q0 = __builtin_shufflevector(qa, qb_, 0,1,2,3,4,5,6,7,8,9,10,11,12,13,14,15);
    c16 Q1 = __builtin_shufflevector(qc, qd, 0,1,2,3,4,5,6,7,8,9,10,11,12,13,14,15);
    *(c16*)(qpyr + (ph + w00) * 8) = Q0;          // 16-B aligned (w00 even)
    *(c16*)(qpyr + (ph + w00 + 512) * 8) = Q1;
    // split int8 mip1
    *(c8*)(qpyr + qoff(1) + ((long)(p * 2 + g) * 65536 + (long)v * 256 + u) * 8) = qo;
}

// fp16 mip -> fp16 mip (+ split-layout int8 copy of the new level)
__global__ __launch_bounds__(256) void ds16(const _Float16* __restrict__ src,
                                            _Float16* __restrict__ dst,
                                            signed char* __restrict__ qlvl, int r2) {
    int idx = blockIdx.x * blockDim.x + threadIdx.x;
    int total = 3 * r2 * r2 * 2;
    if (idx >= total) return;
    int g = idx & 1;
    int rest = idx >> 1;
    int u = rest % r2; rest /= r2;
    int v = rest % r2;
    int p = rest / r2;
    int rs = r2 * 2;
    const h8* s8 = (const h8*)src;
    long t00 = ((long)p * rs + 2 * v) * rs + 2 * u;
    long t01 = t00 + 1, t10 = t00 + rs, t11 = t10 + 1;
    h8 A = s8[t00 * 2 + g], B = s8[t01 * 2 + g], C = s8[t10 * 2 + g], D = s8[t11 * 2 + g];
    h8 o;
    c8 q;
#pragma unroll
    for (int j = 0; j < 8; ++j) {
        float m = ((float)A[j] + (float)B[j] + (float)C[j] + (float)D[j]) * 0.25f;
        o[j] = (_Float16)m;
        q[j] = (signed char)(int)rintf(m * QSCALE);
    }
    ((h8*)dst)[idx] = o;
    *(c8*)(qlvl + ((long)(p * 2 + g) * r2 * r2 + (long)v * r2 + u) * 8) = q;
}

// -------- sampler: 2 lanes per point, split-feature layout ------------------
// lane = i*2 + fg. fg owns 8 features. Each lane loads the contiguous (u0,u1)
// 16-B pair per (level, plane, vrow): 12 dwordx4 gathers per point total.
// No cross-lane reduction needed.
__global__ __launch_bounds__(256) void tm_sample2(const float* __restrict__ x,
                                                  const float* __restrict__ level,
                                                  const signed char* __restrict__ qpyr,
                                                  float* __restrict__ out, int n) {
    int t = blockIdx.x * blockDim.x + threadIdx.x;
    int i = t >> 1;
    if (i >= n) return;
    int fg = t & 1;

    float px = x[3 * i + 0];
    float py = x[3 * i + 1];
    float pz = x[3 * i + 2];
    float lev = fminf(fmaxf(level[i], 0.0f), (float)(NLEV - 1));
    float l0f = floorf(lev);
    float frac = lev - l0f;
    int l0 = (int)l0f;
    int k1 = min(l0 + 1, NLEV - 1);
    int kk[2] = {l0, k1};

    float uu[3] = {py, px, px};
    float vv[3] = {pz, pz, py};
    const float QINV = 1.0f / QSCALE;
    float lw[2] = {(1.0f - frac) * QINV, frac * QINV};

    const signed char* ap[12];
    float wgt[24];
    bool sA[6], sB[6];

#pragma unroll
    for (int s = 0; s < 2; ++s) {
        int k = kk[s];
        int r = BASE >> k;
        float rf = (float)r;
        long lvl = qoff(k);
#pragma unroll
        for (int p = 0; p < 3; ++p) {
            int id = s * 3 + p;
            float cu = uu[p] * rf - 0.5f;
            float cv = vv[p] * rf - 0.5f;
            float fu0 = floorf(cu), fv0 = floorf(cv);
            float fu = cu - fu0, fv = cv - fv0;
            int iu0 = (int)fu0, iv0 = (int)fv0;
            int v0 = min(max(iv0, 0), r - 1);
            int v1 = min(max(iv0 + 1, 0), r - 1);
            int ub = min(max(iu0, 0), r - 2);
            sA[id] = (iu0 >= r - 1);    // A/C take high texel
            sB[id] = (iu0 >= 0);        // B/D take high texel
            const signed char* bp = qpyr + lvl + ((long)(p * 2 + fg) * r * r + ub) * 8;
            ap[id * 2 + 0] = bp + (long)v0 * r * 8;
            ap[id * 2 + 1] = bp + (long)v1 * r * 8;
            float w = lw[s];
            wgt[id * 4 + 0] = (1.0f - fu) * (1.0f - fv) * w;
            wgt[id * 4 + 1] = fu * (1.0f - fv) * w;
            wgt[id * 4 + 2] = (1.0f - fu) * fv * w;
            wgt[id * 4 + 3] = fu * fv * w;
        }
    }

    i4v d[12];
#pragma unroll
    for (int m = 0; m < 12; ++m)
        asm volatile("global_load_dwordx4 %0, %1, off"
                     : "=v"(d[m]) : "v"(ap[m]) : "memory");
    asm volatile("s_waitcnt vmcnt(0)"
                 : "+v"(d[0]), "+v"(d[1]), "+v"(d[2]), "+v"(d[3]),
                   "+v"(d[4]), "+v"(d[5]), "+v"(d[6]), "+v"(d[7]),
                   "+v"(d[8]), "+v"(d[9]), "+v"(d[10]), "+v"(d[11])
                 :: "memory");

    float acc[3][8];
#pragma unroll
    for (int p = 0; p < 3; ++p)
#pragma unroll
        for (int j = 0; j < 8; ++j) acc[p][j] = 0.f;

#pragma unroll
    for (int id = 0; id < 6; ++id) {
        int p = id % 3;
        c16 r0 = __builtin_bit_cast(c16, d[id * 2 + 0]);
        c16 r1 = __builtin_bit_cast(c16, d[id * 2 + 1]);
        c8 lo0 = __builtin_shufflevector(r0, r0, 0,1,2,3,4,5,6,7);
        c8 hi0 = __builtin_shufflevector(r0, r0, 8,9,10,11,12,13,14,15);
        c8 lo1 = __builtin_shufflevector(r1, r1, 0,1,2,3,4,5,6,7);
        c8 hi1 = __builtin_shufflevector(r1, r1, 8,9,10,11,12,13,14,15);
        c8 A = sA[id] ? hi0 : lo0;
        c8 B = sB[id] ? hi0 : lo0;
        c8 C = sA[id] ? hi1 : lo1;
        c8 D = sB[id] ? hi1 : lo1;
        float w00 = wgt[id * 4 + 0], w01 = wgt[id * 4 + 1];
        float w10 = wgt[id * 4 + 2], w11 = wgt[id * 4 + 3];
#pragma unroll
        for (int j = 0; j < 8; ++j)
            acc[p][j] += (float)A[j] * w00 + (float)B[j] * w01
                       + (float)C[j] * w10 + (float)D[j] * w11;
    }

    // out[i*48 + p*16 + fg*8 + j]
    f4v* o4 = (f4v*)out;
    long ob = (long)i * 12 + fg * 2;
#pragma unroll
    for (int p = 0; p < 3; ++p) {
        f4v r0 = {acc[p][0], acc[p][1], acc[p][2], acc[p][3]};
        f4v r1 = {acc[p][4], acc[p][5], acc[p][6], acc[p][7]};
        o4[ob + p * 4 + 0] = r0;
        o4[ob + p * 4 + 1] = r1;
    }
}

extern "C" void kernel_launch(void* const* d_in, const int* in_sizes, int n_in,
                              void* d_out, int out_size, void* d_ws, size_t ws_size,
                              hipStream_t stream) {
    const float* x     = (const float*)d_in[0];
    const float* level = (const float*)d_in[1];
    const float* tex   = (const float*)d_in[2];
    float* out = (float*)d_out;
    signed char* qpyr = (signed char*)d_ws;
    _Float16* wsh = (_Float16*)((char*)d_ws + QPYR_BYTES);
    int n = in_sizes[0] / 3;

    // fused mip build + int8 quantization (split layout)
    {
        int r2 = BASE >> 1;
        int total = 3 * r2 * r2 * 2;
        ds16_first<<<(total + 255) / 256, 256, 0, stream>>>(tex, wsh + moff(1), qpyr, r2);
    }
    for (int k = 2; k < NLEV; ++k) {
        int r2 = BASE >> k;
        int total = 3 * r2 * r2 * 2;
        ds16<<<(total + 255) / 256, 256, 0, stream>>>(wsh + moff(k - 1), wsh + moff(k),
                                                      qpyr + qoff(k), r2);
    }

    long tt = (long)n * 2;
    int blocks = (int)((tt + 255) / 256);
    tm_sample2<<<blocks, 256, 0, stream>>>(x, level, qpyr, out, n);
}